// Round 2
// baseline (510.193 us; speedup 1.0000x reference)
//
#include <hip/hip_runtime.h>
#include <hip/hip_bf16.h>

#define N_ROWS 100000
#define P_DIM 512
#define D_DIM 256
#define TAU 2e-3f

typedef __attribute__((ext_vector_type(4))) float f32x4;
typedef __attribute__((ext_vector_type(8))) short s16x8;

__device__ __forceinline__ unsigned bf16_rne_bits(float x) {
  unsigned u = __float_as_uint(x);
  return (u + 0x7fffu + ((u >> 16) & 1u)) >> 16;
}
__device__ __forceinline__ float bf16_as_float(unsigned bits16) {
  return __uint_as_float(bits16 << 16);
}

// ---------------- prep: patch -> bf16 hi/lo + transposed bf16 ----------------
__global__ void prep_kernel(const float* __restrict__ patch,
                            short* __restrict__ pa_hi, short* __restrict__ pa_lo,
                            short* __restrict__ p_T) {
  int idx = blockIdx.x * 256 + threadIdx.x;
  if (idx >= P_DIM * D_DIM) return;
  float x = patch[idx];
  unsigned hb = bf16_rne_bits(x);
  float hf = bf16_as_float(hb);
  unsigned lb = bf16_rne_bits(x - hf);
  pa_hi[idx] = (short)hb;
  pa_lo[idx] = (short)lb;
  int p = idx >> 8, d = idx & 255;
  p_T[d * P_DIM + p] = (short)hb;
}

// ---------------- main fused kernel ----------------
// block = 256 threads (4 waves), 64 node-rows per block, 16 rows per wave.
__launch_bounds__(256, 2)
__global__ void main_kernel(const float* __restrict__ node,
                            const short* __restrict__ pa_hi,
                            const short* __restrict__ pa_lo,
                            const short* __restrict__ p_T,
                            float* __restrict__ out_hot,
                            float* __restrict__ out_rec,
                            unsigned* __restrict__ suspect) {
  // B1 tile: 64 p-rows x 256 k, +8 short pad per row (row stride 528B = 33*16)
  __shared__ __align__(16) short B1hi[64 * 264];
  __shared__ __align__(16) short B1lo[64 * 264];
  // per-wave P bounce: 16 rows x 64 p-chunk, +8 pad (row stride 144B = 9*16)
  __shared__ __align__(16) short PB[4][16 * 72];

  const int tid  = threadIdx.x;
  const int w    = tid >> 6;
  const int lane = tid & 63;
  const int cc   = lane & 15;
  const int g    = lane >> 4;
  const int wr0  = blockIdx.x * 64 + w * 16;

  // ---- A fragments direct from global, split into bf16 hi/lo ----
  // A-frag: lane holds A[row=lane&15][k = 32*kk + 8*(lane>>4) + j]
  s16x8 ahi[8], alo[8];
  {
    const int r = wr0 + cc;
    const bool ok = (r < N_ROWS);
    const float* nrow = node + (size_t)r * D_DIM;
#pragma unroll
    for (int kk = 0; kk < 8; ++kk) {
      float v[8];
      if (ok) {
        const float4 x0 = *(const float4*)(nrow + kk * 32 + g * 8);
        const float4 x1 = *(const float4*)(nrow + kk * 32 + g * 8 + 4);
        v[0]=x0.x; v[1]=x0.y; v[2]=x0.z; v[3]=x0.w;
        v[4]=x1.x; v[5]=x1.y; v[6]=x1.z; v[7]=x1.w;
      } else {
#pragma unroll
        for (int e = 0; e < 8; ++e) v[e] = 0.f;
      }
#pragma unroll
      for (int e = 0; e < 8; ++e) {
        unsigned hb = bf16_rne_bits(v[e]);
        float hf = bf16_as_float(hb);
        unsigned lb = bf16_rne_bits(v[e] - hf);
        ahi[kk][e] = (short)hb;
        alo[kk][e] = (short)lb;
      }
    }
  }

  // ---- GEMM1: logits[16 rows][512 p] in regs, 3-term split-bf16 ----
  f32x4 acc[32];
  const f32x4 zero4 = {0.f, 0.f, 0.f, 0.f};
#pragma unroll
  for (int t = 0; t < 32; ++t) acc[t] = zero4;

#pragma unroll
  for (int bt = 0; bt < 8; ++bt) {
    __syncthreads();
    {
      const s16x8* srcH = (const s16x8*)(pa_hi + bt * 64 * 256);
      const s16x8* srcL = (const s16x8*)(pa_lo + bt * 64 * 256);
#pragma unroll
      for (int i = 0; i < 8; ++i) {
        int u = i * 256 + tid;            // 2048 16B units
        int rr = u >> 5, cl = (u & 31) * 8;
        *(s16x8*)&B1hi[rr * 264 + cl] = srcH[u];
        *(s16x8*)&B1lo[rr * 264 + cl] = srcL[u];
      }
    }
    __syncthreads();
#pragma unroll
    for (int pt = 0; pt < 4; ++pt) {
      f32x4 a = acc[bt * 4 + pt];
      const int prow = (pt * 16 + cc) * 264;
#pragma unroll
      for (int kk = 0; kk < 8; ++kk) {
        const s16x8 bh = *(const s16x8*)&B1hi[prow + kk * 32 + g * 8];
        const s16x8 bl = *(const s16x8*)&B1lo[prow + kk * 32 + g * 8];
        a = __builtin_amdgcn_mfma_f32_16x16x32_bf16(ahi[kk], bh, a, 0, 0, 0);
        a = __builtin_amdgcn_mfma_f32_16x16x32_bf16(alo[kk], bh, a, 0, 0, 0);
        a = __builtin_amdgcn_mfma_f32_16x16x32_bf16(ahi[kk], bl, a, 0, 0, 0);
      }
      acc[bt * 4 + pt] = a;
    }
  }

  // C layout: lane holds rows (g*4+j), col p = t*16 + cc
  // ---- per-row top-2 (value,index) for argmax + suspect marking ----
  float m1a[4], m2a[4];
  int i1a[4];
#pragma unroll
  for (int j = 0; j < 4; ++j) {
    float m1 = -1e30f, m2 = -1e30f;
    int i1 = 0;
#pragma unroll
    for (int t = 0; t < 32; ++t) {
      float v = acc[t][j];
      int col = t * 16 + cc;
      if (v > m1) { m2 = m1; m1 = v; i1 = col; }
      else if (v > m2) { m2 = v; }
    }
#pragma unroll
    for (int mk = 1; mk <= 8; mk <<= 1) {
      float om1 = __shfl_xor(m1, mk);
      int   oi1 = __shfl_xor(i1, mk);
      float om2 = __shfl_xor(m2, mk);
      if (om1 > m1 || (om1 == m1 && oi1 < i1)) {
        m2 = fmaxf(m1, om2); m1 = om1; i1 = oi1;
      } else {
        m2 = fmaxf(m2, om1);
      }
    }
    m1a[j] = m1; m2a[j] = m2; i1a[j] = i1;
  }

  // dense, deterministic suspect marking (every row written every call)
#pragma unroll
  for (int j = 0; j < 4; ++j) {
    int row = wr0 + g * 4 + j;
    if (cc == 0 && row < N_ROWS)
      suspect[row] = ((m1a[j] - m2a[j]) < TAU) ? 1u : 0u;
  }

  // ---- softmax in registers (exact two-pass over full row) ----
#pragma unroll
  for (int j = 0; j < 4; ++j) {
    float s = 0.f;
#pragma unroll
    for (int t = 0; t < 32; ++t) {
      float e = __expf(acc[t][j] - m1a[j]);
      acc[t][j] = e;
      s += e;
    }
#pragma unroll
    for (int mk = 1; mk <= 8; mk <<= 1) s += __shfl_xor(s, mk);
    float inv = 1.0f / s;
#pragma unroll
    for (int t = 0; t < 32; ++t) acc[t][j] *= inv;
  }

  // ---- one-hot output (straight-through estimator forward value) ----
#pragma unroll
  for (int j2 = 0; j2 < 16; ++j2) {
    int winner = __shfl(i1a[j2 & 3], (j2 >> 2) * 16);
    int row = wr0 + j2;
    if (row < N_ROWS) {
      int base = lane * 8;
      float4 z0, z1;
      z0.x = (winner == base + 0) ? 1.f : 0.f;
      z0.y = (winner == base + 1) ? 1.f : 0.f;
      z0.z = (winner == base + 2) ? 1.f : 0.f;
      z0.w = (winner == base + 3) ? 1.f : 0.f;
      z1.x = (winner == base + 4) ? 1.f : 0.f;
      z1.y = (winner == base + 5) ? 1.f : 0.f;
      z1.z = (winner == base + 6) ? 1.f : 0.f;
      z1.w = (winner == base + 7) ? 1.f : 0.f;
      float* orow = out_hot + (size_t)row * P_DIM + base;
      *(float4*)orow = z0;
      *(float4*)(orow + 4) = z1;
    }
  }

  // ---- GEMM2: out_rec[16 rows][256 d] = P @ patch, P bounced via LDS ----
  f32x4 acc2[16];
#pragma unroll
  for (int dt = 0; dt < 16; ++dt) acc2[dt] = zero4;

  short* pb = &PB[w][0];
#pragma unroll
  for (int pch = 0; pch < 8; ++pch) {
    // ensure previous iteration's reads are fully serviced before overwrite
    asm volatile("s_waitcnt lgkmcnt(0)" ::: "memory");
    // bounce this 64-wide p-chunk of P to LDS as bf16 (C-layout -> row-major)
#pragma unroll
    for (int tt = 0; tt < 4; ++tt) {
#pragma unroll
      for (int j = 0; j < 4; ++j) {
        pb[(g * 4 + j) * 72 + tt * 16 + cc] = (short)bf16_rne_bits(acc[pch * 4 + tt][j]);
      }
    }
    // same-wave LDS RAW fence: writes complete before the reads below
    asm volatile("s_waitcnt lgkmcnt(0)" ::: "memory");
#pragma unroll
    for (int kk2 = 0; kk2 < 2; ++kk2) {
      const s16x8 a2 = *(const s16x8*)&pb[cc * 72 + kk2 * 32 + g * 8];
#pragma unroll
      for (int dt = 0; dt < 16; ++dt) {
        const s16x8 b2 = *(const s16x8*)(p_T + (size_t)(dt * 16 + cc) * P_DIM + pch * 64 + kk2 * 32 + g * 8);
        acc2[dt] = __builtin_amdgcn_mfma_f32_16x16x32_bf16(a2, b2, acc2[dt], 0, 0, 0);
      }
    }
  }

#pragma unroll
  for (int dt = 0; dt < 16; ++dt) {
#pragma unroll
    for (int j = 0; j < 4; ++j) {
      int row = wr0 + g * 4 + j;
      if (row < N_ROWS)
        out_rec[(size_t)row * D_DIM + dt * 16 + cc] = acc2[dt][j];
    }
  }
}

// ---------------- refine: exact fp64 argmax for suspect rows (dense scan) ----
// one wave (64 threads) per 64-row chunk; deterministic, no atomics.
__global__ void refine_kernel(const float* __restrict__ node,
                              const float* __restrict__ patch,
                              const unsigned* __restrict__ suspect,
                              float* __restrict__ out_hot) {
  __shared__ double nd[256];
  const int lane = threadIdx.x;          // blockDim.x == 64
  const int r0 = blockIdx.x * 64;
  const int r = r0 + lane;
  unsigned s = (r < N_ROWS) ? suspect[r] : 0u;
  unsigned long long mask = __ballot(s != 0u);
  while (mask) {
    int src = __ffsll((long long)mask) - 1;
    mask &= mask - 1;
    int row = r0 + src;
    // stage node row as fp64 in LDS
#pragma unroll
    for (int q = 0; q < 4; ++q)
      nd[q * 64 + lane] = (double)node[(size_t)row * D_DIM + q * 64 + lane];
    __syncthreads();   // single-wave block: uniform, orders LDS write->read
    double bv = -1e300;
    int bi = 0;
#pragma unroll
    for (int pp = 0; pp < 8; ++pp) {
      int p = lane * 8 + pp;
      const float* pr = patch + (size_t)p * D_DIM;
      double sacc = 0.0;
#pragma unroll 4
      for (int k = 0; k < 256; k += 4) {
        float4 f = *(const float4*)(pr + k);
        sacc += nd[k]   * (double)f.x + nd[k+1] * (double)f.y
              + nd[k+2] * (double)f.z + nd[k+3] * (double)f.w;
      }
      if (sacc > bv) { bv = sacc; bi = p; }          // ascending p, strict >
    }
#pragma unroll
    for (int mk = 1; mk < 64; mk <<= 1) {
      double ov = __shfl_xor(bv, mk);
      int    oi = __shfl_xor(bi, mk);
      if (ov > bv || (ov == bv && oi < bi)) { bv = ov; bi = oi; }
    }
    // rewrite the entire one-hot row (no dependence on provisional winner)
    {
      int base = lane * 8;
      float* orow = out_hot + (size_t)row * P_DIM + base;
      float4 z0, z1;
      z0.x = (bi == base + 0) ? 1.f : 0.f;
      z0.y = (bi == base + 1) ? 1.f : 0.f;
      z0.z = (bi == base + 2) ? 1.f : 0.f;
      z0.w = (bi == base + 3) ? 1.f : 0.f;
      z1.x = (bi == base + 4) ? 1.f : 0.f;
      z1.y = (bi == base + 5) ? 1.f : 0.f;
      z1.z = (bi == base + 6) ? 1.f : 0.f;
      z1.w = (bi == base + 7) ? 1.f : 0.f;
      *(float4*)orow = z0;
      *(float4*)(orow + 4) = z1;
    }
    __syncthreads();   // nd reuse barrier for next suspect in this chunk
  }
}

extern "C" void kernel_launch(void* const* d_in, const int* in_sizes, int n_in,
                              void* d_out, int out_size, void* d_ws, size_t ws_size,
                              hipStream_t stream) {
  const float* node  = (const float*)d_in[0];
  const float* patch = (const float*)d_in[1];
  float* out_hot = (float*)d_out;
  float* out_rec = out_hot + (size_t)N_ROWS * P_DIM;

  char* ws = (char*)d_ws;
  short* pa_hi = (short*)ws;
  short* pa_lo = pa_hi + P_DIM * D_DIM;
  short* p_T   = pa_lo + P_DIM * D_DIM;
  unsigned* suspect = (unsigned*)(ws + (size_t)3 * P_DIM * D_DIM * sizeof(short));

  prep_kernel<<<512, 256, 0, stream>>>(patch, pa_hi, pa_lo, p_T);
  main_kernel<<<(N_ROWS + 63) / 64, 256, 0, stream>>>(node, pa_hi, pa_lo, p_T,
                                                      out_hot, out_rec, suspect);
  refine_kernel<<<(N_ROWS + 63) / 64, 64, 0, stream>>>(node, patch, suspect, out_hot);
}

// Round 3
// 419.770 us; speedup vs baseline: 1.2154x; 1.2154x over previous
//
#include <hip/hip_runtime.h>
#include <hip/hip_bf16.h>

#define N_ROWS 100000
#define P_DIM 512
#define D_DIM 256
#define TAU 1e-2f

typedef __attribute__((ext_vector_type(4))) float f32x4;
typedef __attribute__((ext_vector_type(8))) short s16x8;

__device__ __forceinline__ unsigned bf16_rne_bits(float x) {
  unsigned u = __float_as_uint(x);
  return (u + 0x7fffu + ((u >> 16) & 1u)) >> 16;
}
__device__ __forceinline__ float bf16_as_float(unsigned b) {
  return __uint_as_float(b << 16);
}

// ---------------- prep ----------------
// blocks 0..63:  pa_swz  — patch_hi bf16, 8 tiles of [64 p][256 d], rows
//                XOR-swizzled (byte ^= (row&7)<<4) so main stages LINEARLY
//                and reads conflict-free.
// blocks 64..127: p_T_perm — patch_hi bf16 transposed [d][p] with the GEMM2
//                k-permutation p(kc,g,j) = 32kc + 16*(j>>2) + 4g + (j&3)
//                baked in; unit index = (d*16 + kc)*4 + g, 8 shorts each.
__global__ void prep_kernel(const float* __restrict__ patch,
                            short* __restrict__ pa_swz,
                            short* __restrict__ p_T_perm) {
  int b = blockIdx.x, t = threadIdx.x;
  if (b < 64) {
    int u = b * 256 + t;                  // 16384 16B-units total
    int bt = u >> 11;                     // 2048 units per 32KB tile
    int Lb = (u & 2047) * 16;             // dest byte within tile
    int r  = Lb >> 9;                     // p-row in tile (512B rows)
    int srcb = Lb ^ ((r & 7) << 4);       // involutive swizzle
    int p = bt * 64 + r;
    int d0 = (srcb & 511) >> 1;
    s16x8 v;
#pragma unroll
    for (int q = 0; q < 8; ++q)
      v[q] = (short)bf16_rne_bits(patch[(size_t)p * D_DIM + d0 + q]);
    *(s16x8*)(pa_swz + (size_t)u * 8) = v;
  } else {
    int u = (b - 64) * 256 + t;           // 16384 units
    int g = u & 3, kc = (u >> 2) & 15, d = u >> 6;
    s16x8 v;
#pragma unroll
    for (int j = 0; j < 8; ++j) {
      int p = 32 * kc + 16 * (j >> 2) + 4 * g + (j & 3);
      v[j] = (short)bf16_rne_bits(patch[(size_t)p * D_DIM + d]);
    }
    *(s16x8*)(p_T_perm + (size_t)u * 8) = v;
  }
}

// ---------------- main fused kernel ----------------
// 4 waves/block, 16 node-rows per wave (as MFMA COLUMNS).
// GEMM1 (transposed): C1[p=512][16 rows] per wave, A=patch tile (LDS),
// B=node hi/lo frags (regs). Softmax per-lane. GEMM2: A=p_T_perm (L2),
// B=probs repacked in-register (free transpose via shared k-perm).
__launch_bounds__(256, 2)
__global__ void main_kernel(const float* __restrict__ node,
                            const short* __restrict__ pa_swz,
                            const short* __restrict__ p_T_perm,
                            float* __restrict__ out_hot,
                            float* __restrict__ out_rec,
                            unsigned* __restrict__ suspect) {
  __shared__ __align__(16) char B1[2][32768];   // double-buffered patch tile

  const int tid = threadIdx.x;
  const int w = tid >> 6, lane = tid & 63;
  const int cc = lane & 15, g = lane >> 4;
  const int myrow = blockIdx.x * 64 + w * 16 + cc;
  const bool ok = myrow < N_ROWS;

  // ---- node B-frags, split hi/lo: elem j <-> k = kk*32 + 8g + j ----
  s16x8 nhi[8], nlo[8];
  {
    const float* nr = node + (size_t)myrow * D_DIM;
#pragma unroll
    for (int kk = 0; kk < 8; ++kk) {
      float v[8];
      if (ok) {
        float4 x0 = *(const float4*)(nr + kk * 32 + g * 8);
        float4 x1 = *(const float4*)(nr + kk * 32 + g * 8 + 4);
        v[0]=x0.x; v[1]=x0.y; v[2]=x0.z; v[3]=x0.w;
        v[4]=x1.x; v[5]=x1.y; v[6]=x1.z; v[7]=x1.w;
      } else {
#pragma unroll
        for (int e = 0; e < 8; ++e) v[e] = 0.f;
      }
#pragma unroll
      for (int e = 0; e < 8; ++e) {
        unsigned hb = bf16_rne_bits(v[e]);
        nhi[kk][e] = (short)hb;
        nlo[kk][e] = (short)bf16_rne_bits(v[e] - bf16_as_float(hb));
      }
    }
  }

  // ---- GEMM1 ----
  f32x4 acc[32];
#pragma unroll
  for (int t = 0; t < 32; ++t) acc[t] = (f32x4){0.f, 0.f, 0.f, 0.f};

  const s16x8* srcu = (const s16x8*)pa_swz;
  {  // prologue: stage tile 0
    s16x8 st[8];
#pragma unroll
    for (int i = 0; i < 8; ++i) st[i] = srcu[i * 256 + tid];
#pragma unroll
    for (int i = 0; i < 8; ++i)
      *(s16x8*)(&B1[0][(i * 256 + tid) * 16]) = st[i];
  }
  __syncthreads();

#pragma unroll
  for (int bt = 0; bt < 8; ++bt) {
    const int cur = bt & 1;
    s16x8 st[8];
    if (bt < 7) {         // issue next-tile loads early; hide under MFMA
#pragma unroll
      for (int i = 0; i < 8; ++i)
        st[i] = srcu[(bt + 1) * 2048 + i * 256 + tid];
    }
#pragma unroll
    for (int pt = 0; pt < 4; ++pt) {
      f32x4 a = acc[bt * 4 + pt];
#pragma unroll
      for (int kk = 0; kk < 8; ++kk) {
        int ad = (((pt * 16 + cc) << 9) + (kk << 6) + (g << 4)) ^ ((cc & 7) << 4);
        s16x8 af = *(const s16x8*)(&B1[cur][ad]);
        a = __builtin_amdgcn_mfma_f32_16x16x32_bf16(af, nhi[kk], a, 0, 0, 0);
        a = __builtin_amdgcn_mfma_f32_16x16x32_bf16(af, nlo[kk], a, 0, 0, 0);
      }
      acc[bt * 4 + pt] = a;
    }
    __syncthreads();                       // all waves done reading B1[cur^1... prev]
    if (bt < 7) {
#pragma unroll
      for (int i = 0; i < 8; ++i)
        *(s16x8*)(&B1[cur ^ 1][(i * 256 + tid) * 16]) = st[i];
    }
    __syncthreads();                       // writes visible
  }

  // C1 layout: lane (cc,g) reg j of tile t = logits[p = 16t+4g+j][row cc]
  // ---- per-lane top-3 scan (ascending p => strict > keeps lowest index) ----
  float m1 = -1e30f, m2 = -1e30f, m3 = -1e30f;
  int i1 = 0, i2 = 0;
#pragma unroll
  for (int t = 0; t < 32; ++t) {
#pragma unroll
    for (int j = 0; j < 4; ++j) {
      float v = acc[t][j];
      int col = 16 * t + 4 * g + j;
      bool g1 = v > m1, g2 = v > m2, g3 = v > m3;
      m3 = g2 ? m2 : (g3 ? v : m3);
      i2 = g1 ? i1 : (g2 ? col : i2);
      m2 = g1 ? m1 : (g2 ? v : m2);
      i1 = g1 ? col : i1;
      m1 = g1 ? v : m1;
    }
  }
  // merge across the 4 g-lanes of each row (lanes differ in bits 4-5)
#pragma unroll
  for (int mk = 16; mk <= 32; mk <<= 1) {
    float bm1 = __shfl_xor(m1, mk); int bi1 = __shfl_xor(i1, mk);
    float bm2 = __shfl_xor(m2, mk); int bi2 = __shfl_xor(i2, mk);
    float bm3 = __shfl_xor(m3, mk);
    bool sw = (bm1 > m1) || (bm1 == m1 && bi1 < i1);
    float am1 = sw ? bm1 : m1; int ai1 = sw ? bi1 : i1;
    float am2 = sw ? bm2 : m2; int ai2 = sw ? bi2 : i2;
    float am3 = sw ? bm3 : m3;
    float cm1 = sw ? m1 : bm1; int ci1 = sw ? i1 : bi1;
    float cm2 = sw ? m2 : bm2;
    bool t2b = (cm1 > am2) || (cm1 == am2 && ci1 < ai2);
    m1 = am1; i1 = ai1;
    m2 = t2b ? cm1 : am2; i2 = t2b ? ci1 : ai2;
    m3 = t2b ? fmaxf(am2, cm2) : fmaxf(am3, cm1);
  }

  // dense deterministic suspect record: candidates i1,i2 (+full flag)
  if (g == 0 && ok) {
    unsigned codev = 0u;
    if (m1 - m2 < TAU)
      codev = 0x80000000u | ((m1 - m3 < TAU) ? 0x40000000u : 0u)
            | ((unsigned)i2 << 9) | (unsigned)i1;
    suspect[myrow] = codev;
  }

  // ---- softmax: single per-lane sum + 2 shuffles ----
  float s = 0.f;
#pragma unroll
  for (int t = 0; t < 32; ++t) {
#pragma unroll
    for (int j = 0; j < 4; ++j) {
      float e = __expf(acc[t][j] - m1);
      acc[t][j] = e;
      s += e;
    }
  }
  s += __shfl_xor(s, 16);
  s += __shfl_xor(s, 32);
  const float inv = 1.0f / s;

  // ---- one-hot write (4 g-lanes cover 64B contiguous per row) ----
  if (ok) {
    float* orow = out_hot + (size_t)myrow * P_DIM;
#pragma unroll
    for (int c2 = 0; c2 < 32; ++c2) {
      int col = c2 * 16 + g * 4;
      f32x4 z;
      z[0] = (i1 == col + 0) ? 1.f : 0.f;
      z[1] = (i1 == col + 1) ? 1.f : 0.f;
      z[2] = (i1 == col + 2) ? 1.f : 0.f;
      z[3] = (i1 == col + 3) ? 1.f : 0.f;
      *(f32x4*)(orow + col) = z;
    }
  }

  // ---- GEMM2: C2[d][row] = patch^T @ P ; B-frags = probs in-register ----
  s16x8 pf[16];
#pragma unroll
  for (int kc = 0; kc < 16; ++kc) {
    s16x8 f;
#pragma unroll
    for (int j = 0; j < 4; ++j) {
      f[j]     = (short)bf16_rne_bits(acc[2 * kc][j] * inv);
      f[j + 4] = (short)bf16_rne_bits(acc[2 * kc + 1][j] * inv);
    }
    pf[kc] = f;
  }
  const s16x8* pT = (const s16x8*)p_T_perm;
#pragma unroll
  for (int t2 = 0; t2 < 16; ++t2) {
    s16x8 a2[16];
    const int ub = (16 * t2 + cc) * 64 + g;
#pragma unroll
    for (int kc = 0; kc < 16; ++kc) a2[kc] = pT[ub + kc * 4];
    f32x4 c2 = (f32x4){0.f, 0.f, 0.f, 0.f};
#pragma unroll
    for (int kc = 0; kc < 16; ++kc)
      c2 = __builtin_amdgcn_mfma_f32_16x16x32_bf16(a2[kc], pf[kc], c2, 0, 0, 0);
    if (ok)
      *(f32x4*)(out_rec + (size_t)myrow * D_DIM + 16 * t2 + 4 * g) = c2;
  }
}

// ---------------- refine: fp64 check of the 2 candidates (dense scan) ------
__global__ void refine_kernel(const float* __restrict__ node,
                              const float* __restrict__ patch,
                              const unsigned* __restrict__ suspect,
                              float* __restrict__ out_hot) {
  const int lane = threadIdx.x;            // blockDim.x == 64
  const int r0 = blockIdx.x * 64;
  unsigned code = (r0 + lane < N_ROWS) ? suspect[r0 + lane] : 0u;
  unsigned long long mask = __ballot(code != 0u);
  while (mask) {
    int src = __ffsll((long long)mask) - 1;
    mask &= mask - 1;
    unsigned c = __shfl(code, src);
    int row = r0 + src;
    int i1 = (int)(c & 511u), i2 = (int)((c >> 9) & 511u);
    if (!(c & 0x40000000u)) {
      // exact fp64 dots for the two candidates; halves of the wave split them
      int pidx = (lane >= 32) ? i2 : i1;
      int l5 = lane & 31;
      double sd = 0.0;
#pragma unroll
      for (int q = 0; q < 8; ++q) {
        int d = l5 * 8 + q;
        sd += (double)node[(size_t)row * D_DIM + d] *
              (double)patch[(size_t)pidx * D_DIM + d];
      }
#pragma unroll
      for (int mk = 1; mk <= 16; mk <<= 1) sd += __shfl_xor(sd, mk);
      double d1 = __shfl(sd, 0), d2 = __shfl(sd, 32);
      int win = (d2 > d1) ? i2 : ((d2 == d1) ? (i1 < i2 ? i1 : i2) : i1);
      if (lane == 0) {
        out_hot[(size_t)row * P_DIM + i1] = (win == i1) ? 1.f : 0.f;
        out_hot[(size_t)row * P_DIM + i2] = (win == i2) ? 1.f : 0.f;
      }
    } else {
      // rare: full exact 512-way argmax, rewrite whole row
      double bv = -1e300;
      int bi = 0;
#pragma unroll 1
      for (int pp = 0; pp < 8; ++pp) {
        int p = pp * 64 + lane;
        double sd = 0.0;
        for (int d = 0; d < 256; d += 4) {
          float4 f = *(const float4*)(patch + (size_t)p * D_DIM + d);
          sd += (double)node[(size_t)row * D_DIM + d]     * (double)f.x
              + (double)node[(size_t)row * D_DIM + d + 1] * (double)f.y
              + (double)node[(size_t)row * D_DIM + d + 2] * (double)f.z
              + (double)node[(size_t)row * D_DIM + d + 3] * (double)f.w;
        }
        if (sd > bv) { bv = sd; bi = p; }   // ascending p, strict >
      }
#pragma unroll
      for (int mk = 1; mk < 64; mk <<= 1) {
        double ov = __shfl_xor(bv, mk);
        int oi = __shfl_xor(bi, mk);
        if (ov > bv || (ov == bv && oi < bi)) { bv = ov; bi = oi; }
      }
      int base = lane * 8;
      f32x4 z0, z1;
#pragma unroll
      for (int q = 0; q < 4; ++q) {
        z0[q] = (bi == base + q) ? 1.f : 0.f;
        z1[q] = (bi == base + 4 + q) ? 1.f : 0.f;
      }
      *(f32x4*)(out_hot + (size_t)row * P_DIM + base) = z0;
      *(f32x4*)(out_hot + (size_t)row * P_DIM + base + 4) = z1;
    }
  }
}

extern "C" void kernel_launch(void* const* d_in, const int* in_sizes, int n_in,
                              void* d_out, int out_size, void* d_ws, size_t ws_size,
                              hipStream_t stream) {
  const float* node  = (const float*)d_in[0];
  const float* patch = (const float*)d_in[1];
  float* out_hot = (float*)d_out;
  float* out_rec = out_hot + (size_t)N_ROWS * P_DIM;

  char* ws = (char*)d_ws;
  short* pa_swz   = (short*)ws;                                   // 256 KB
  short* p_T_perm = pa_swz + 131072;                              // 256 KB
  unsigned* suspect = (unsigned*)(ws + 2 * 262144);               // 400 KB

  prep_kernel<<<128, 256, 0, stream>>>(patch, pa_swz, p_T_perm);
  main_kernel<<<(N_ROWS + 63) / 64, 256, 0, stream>>>(node, pa_swz, p_T_perm,
                                                      out_hot, out_rec, suspect);
  refine_kernel<<<(N_ROWS + 63) / 64, 64, 0, stream>>>(node, patch, suspect, out_hot);
}